// Round 6
// baseline (221.589 us; speedup 1.0000x reference)
//
#include <hip/hip_runtime.h>
#include <stdint.h>

// R5: DIAGNOSTIC ROUND. Three load-only probes (linear, nontemporal, exact
// gemm-pattern) + unchanged R4 GEMM. Each shows up as its own dispatch in
// rocprof; the split between their durations identifies the ~2.5 TB/s cap:
// platform read ceiling vs access pattern vs sync structure.

#define WT_SHORTS  (512 * 64)       // 32768 bf16 = 64 KB
#define WT_BYTES   (WT_SHORTS * 2)
#define XPAN_BYTES (256 * 64 * 2)   // 32 KB per buffer

typedef __bf16 bf16x8 __attribute__((ext_vector_type(8)));
typedef __bf16 bf16x4 __attribute__((ext_vector_type(4)));
typedef float  f32x4  __attribute__((ext_vector_type(4)));

// ---------------- probes ----------------

__global__ __launch_bounds__(256)
void probe_lin(const float* __restrict__ xa, const float* __restrict__ xb) {
    const size_t NV = 4194304;  // f32x4 per array (65536*256/4)
    const f32x4* A = (const f32x4*)xa;
    const f32x4* B = (const f32x4*)xb;
    size_t tid    = (size_t)blockIdx.x * 256 + threadIdx.x;
    size_t stride = (size_t)gridDim.x * 256;
    f32x4 s0 = {0.f,0.f,0.f,0.f}, s1 = s0, s2 = s0, s3 = s0;
    for (size_t i = tid; i + 3 * stride < NV; i += 4 * stride) {
        s0 += A[i];
        s1 += A[i + stride];
        s2 += A[i + 2 * stride];
        s3 += A[i + 3 * stride];
    }
    for (size_t i = tid; i + 3 * stride < NV; i += 4 * stride) {
        s0 += B[i];
        s1 += B[i + stride];
        s2 += B[i + 2 * stride];
        s3 += B[i + 3 * stride];
    }
    f32x4 s = s0 + s1 + s2 + s3;
    asm volatile("" :: "v"(s[0]), "v"(s[1]), "v"(s[2]), "v"(s[3]));
}

__global__ __launch_bounds__(256)
void probe_nt(const float* __restrict__ xa, const float* __restrict__ xb) {
    const size_t NV = 4194304;
    const f32x4* A = (const f32x4*)xa;
    const f32x4* B = (const f32x4*)xb;
    size_t tid    = (size_t)blockIdx.x * 256 + threadIdx.x;
    size_t stride = (size_t)gridDim.x * 256;
    f32x4 s0 = {0.f,0.f,0.f,0.f}, s1 = s0, s2 = s0, s3 = s0;
    for (size_t i = tid; i + 3 * stride < NV; i += 4 * stride) {
        s0 += __builtin_nontemporal_load(&A[i]);
        s1 += __builtin_nontemporal_load(&A[i + stride]);
        s2 += __builtin_nontemporal_load(&A[i + 2 * stride]);
        s3 += __builtin_nontemporal_load(&A[i + 3 * stride]);
    }
    for (size_t i = tid; i + 3 * stride < NV; i += 4 * stride) {
        s0 += __builtin_nontemporal_load(&B[i]);
        s1 += __builtin_nontemporal_load(&B[i + stride]);
        s2 += __builtin_nontemporal_load(&B[i + 2 * stride]);
        s3 += __builtin_nontemporal_load(&B[i + 3 * stride]);
    }
    f32x4 s = s0 + s1 + s2 + s3;
    asm volatile("" :: "v"(s[0]), "v"(s[1]), "v"(s[2]), "v"(s[3]));
}

// exact R4 staging address stream, minus LDS/MFMA/barriers
__global__ __launch_bounds__(1024)
void probe_gpat(const float* __restrict__ xa, const float* __restrict__ xb) {
    const int t    = threadIdx.x;
    const int srow = t >> 4;
    const int sp   = t & 15;
    const int row0 = blockIdx.x * 256;
    f32x4 s = {0.f,0.f,0.f,0.f};
    #pragma unroll
    for (int c = 0; c < 8; ++c) {
        const float* src = ((c < 4) ? xa : xb)
                         + (size_t)row0 * 256 + (c & 3) * 64 + sp * 4;
        #pragma unroll
        for (int j = 0; j < 4; ++j)
            s += *(const f32x4*)(src + (size_t)(j * 64 + srow) * 256);
    }
    asm volatile("" :: "v"(s[0]), "v"(s[1]), "v"(s[2]), "v"(s[3]));
}

// ---------------- weights prep (unchanged) ----------------

__global__ void prep_wt_kernel(const float* __restrict__ wa,
                               const float* __restrict__ wb,
                               __bf16* __restrict__ wt) {
    int o2 = blockIdx.x * 256 + threadIdx.x;
    #pragma unroll
    for (int h = 0; h < 2; ++h) {
        int o    = o2 * 2 + h;
        int j    = o & 7;
        int lane = (o >> 3) & 63;
        int cb   = (o >> 9) & 3;
        int s    = o >> 11;
        int k    = s * 32 + (lane >> 4) * 8 + j;
        int col  = (lane & 15) + cb * 16;
        float v  = (k < 256) ? wa[k * 64 + col] : wb[(k - 256) * 64 + col];
        wt[o] = (__bf16)v;
    }
}

// ---------------- GEMM (unchanged R4) ----------------

template <bool USE_WS>
__global__ __launch_bounds__(1024, 4)
void agg_gemm_kernel(const float* __restrict__ xa,
                     const float* __restrict__ xb,
                     const float* __restrict__ wa,
                     const float* __restrict__ wb,
                     const __bf16* __restrict__ wt,
                     float* __restrict__ out) {
    __shared__ __align__(16) __bf16 wlds[WT_SHORTS];
    __shared__ __align__(16) __bf16 xpan[2 * 256 * 64];

    const int t    = threadIdx.x;
    const int lane = t & 63;
    const int wave = t >> 6;

    if (USE_WS) {
        const f32x4* g = (const f32x4*)wt;
        f32x4*       l = (f32x4*)&wlds[0];
        #pragma unroll
        for (int it = 0; it < 4; ++it)
            l[it * 1024 + t] = g[it * 1024 + t];
    } else {
        for (int i = 0; i < 32; ++i) {
            int o    = t * 32 + i;
            int j    = o & 7;
            int ln   = (o >> 3) & 63;
            int cb   = (o >> 9) & 3;
            int s    = o >> 11;
            int k    = s * 32 + (ln >> 4) * 8 + j;
            int col  = (ln & 15) + cb * 16;
            wlds[o] = (__bf16)((k < 256) ? wa[k * 64 + col]
                                         : wb[(k - 256) * 64 + col]);
        }
    }

    const int row0 = blockIdx.x * 256;
    const int srow = t >> 4;
    const int sp   = t & 15;

    auto issue = [&](int c, f32x4 (&r)[4]) {
        const float* src = ((c < 4) ? xa : xb)
                         + (size_t)row0 * 256 + (c & 3) * 64 + sp * 4;
        #pragma unroll
        for (int j = 0; j < 4; ++j)
            r[j] = *(const f32x4*)(src + (size_t)(j * 64 + srow) * 256);
    };

    auto lds_write = [&](int c, const f32x4 (&r)[4]) {
        char* buf = (char*)xpan + (c & 1) * XPAN_BYTES;
        #pragma unroll
        for (int j = 0; j < 4; ++j) {
            int row = j * 64 + srow;
            bf16x4 v;
            v[0] = (__bf16)r[j][0]; v[1] = (__bf16)r[j][1];
            v[2] = (__bf16)r[j][2]; v[3] = (__bf16)r[j][3];
            *(bf16x4*)(buf + ((row * 128 + sp * 8) ^ ((row & 7) << 4))) = v;
        }
    };

    const int r_     = lane & 15;
    const int kg     = lane >> 4;
    const int prow   = wave * 16 + r_;
    const int xbyte0 = prow * 128 + kg * 16;
    const int xsw    = (r_ & 7) << 4;

    f32x4 acc0 = {0.f, 0.f, 0.f, 0.f};
    f32x4 acc1 = acc0, acc2 = acc0, acc3 = acc0;

    auto mstep = [&](int c) {
        const char* buf = (const char*)xpan + (c & 1) * XPAN_BYTES;
        #pragma unroll
        for (int s = 0; s < 2; ++s) {
            bf16x8 af = *(const bf16x8*)(buf + ((xbyte0 + s * 64) ^ xsw));
            const int sg = c * 2 + s;
            const __bf16* w0p = &wlds[(sg * 4) * 512 + lane * 8];
            bf16x8 w0 = *(const bf16x8*)(w0p);
            bf16x8 w1 = *(const bf16x8*)(w0p + 512);
            bf16x8 w2 = *(const bf16x8*)(w0p + 1024);
            bf16x8 w3 = *(const bf16x8*)(w0p + 1536);
            acc0 = __builtin_amdgcn_mfma_f32_16x16x32_bf16(af, w0, acc0, 0, 0, 0);
            acc1 = __builtin_amdgcn_mfma_f32_16x16x32_bf16(af, w1, acc1, 0, 0, 0);
            acc2 = __builtin_amdgcn_mfma_f32_16x16x32_bf16(af, w2, acc2, 0, 0, 0);
            acc3 = __builtin_amdgcn_mfma_f32_16x16x32_bf16(af, w3, acc3, 0, 0, 0);
        }
    };

    f32x4 rA[4], rB[4];
    issue(0, rA);
    issue(1, rB);
    lds_write(0, rA);
    asm volatile("s_waitcnt lgkmcnt(0)" ::: "memory");
    __builtin_amdgcn_s_barrier();

    #pragma unroll
    for (int c = 0; c < 8; ++c) {
        if (c < 6) {
            if (c & 1) issue(c + 2, rB); else issue(c + 2, rA);
            __builtin_amdgcn_sched_barrier(0);
        }
        if (c < 7) {
            if (c & 1) lds_write(c + 1, rA); else lds_write(c + 1, rB);
        }
        mstep(c);
        asm volatile("s_waitcnt lgkmcnt(0)" ::: "memory");
        __builtin_amdgcn_s_barrier();
    }

    float* po = out + (size_t)(row0 + wave * 16 + kg * 4) * 64 + r_;
    #pragma unroll
    for (int r = 0; r < 4; ++r) {
        po[r * 64 +  0] = acc0[r];
        po[r * 64 + 16] = acc1[r];
        po[r * 64 + 32] = acc2[r];
        po[r * 64 + 48] = acc3[r];
    }
}

extern "C" void kernel_launch(void* const* d_in, const int* in_sizes, int n_in,
                              void* d_out, int out_size, void* d_ws, size_t ws_size,
                              hipStream_t stream) {
    const float* xa = (const float*)d_in[0];
    const float* xb = (const float*)d_in[1];
    const float* wa = (const float*)d_in[2];
    const float* wb = (const float*)d_in[3];
    float* out = (float*)d_out;

    // diagnostic probes (read-only; keepalive via inline asm, no stores)
    probe_lin <<<1024, 256, 0, stream>>>(xa, xb);
    probe_nt  <<<1024, 256, 0, stream>>>(xa, xb);
    probe_gpat<<<256, 1024, 0, stream>>>(xa, xb);

    if (ws_size >= (size_t)WT_BYTES) {
        __bf16* wt = (__bf16*)d_ws;
        prep_wt_kernel<<<64, 256, 0, stream>>>(wa, wb, wt);
        agg_gemm_kernel<true><<<256, 1024, 0, stream>>>(xa, xb, wa, wb, wt, out);
    } else {
        agg_gemm_kernel<false><<<256, 1024, 0, stream>>>(xa, xb, wa, wb, nullptr, out);
    }
}

// Round 7
// 159.725 us; speedup vs baseline: 1.3873x; 1.3873x over previous
//
#include <hip/hip_runtime.h>
#include <stdint.h>

// out[65536,64] = xa[65536,256] @ wa[256,64] + xb[65536,256] @ wb[256,64]
// R5 diagnostics: best linear first-read of this working set = 43-45us
// (3.1 TB/s, 50% L3-hit after harness restore); GEMM structure runs <42.5us
// when L3-hot. R6: probe-like GEMM — zero barriers, wave-autonomous 4KB LDS
// transpose buffers, weights per-fragment from L2 (prepped d_ws layout),
// deep per-wave load pipeline. Target: the ~43-45us streaming floor + eps.

#define WT_SHORTS (512 * 64)       // 32768 bf16 = 64 KB
#define WT_BYTES  (WT_SHORTS * 2)

typedef __bf16 bf16x8 __attribute__((ext_vector_type(8)));
typedef __bf16 bf16x4 __attribute__((ext_vector_type(4)));
typedef float  f32x4  __attribute__((ext_vector_type(4)));

// Fragment-native weight layout in d_ws (R2-verified):
//   wt[((sg*4 + cb)*64 + lane)*8 + j] = W[k][col],
//   k = sg*32 + (lane>>4)*8 + j  (k<256 -> wa, else wb), col = (lane&15)+cb*16.
// Wave frag read = contiguous 1KB from L2.
__global__ void prep_wt_kernel(const float* __restrict__ wa,
                               const float* __restrict__ wb,
                               __bf16* __restrict__ wt) {
    int o2 = blockIdx.x * 256 + threadIdx.x;   // 0..16383
    #pragma unroll
    for (int h = 0; h < 2; ++h) {
        int o    = o2 * 2 + h;                 // 0..32767
        int j    = o & 7;
        int lane = (o >> 3) & 63;
        int cb   = (o >> 9) & 3;
        int s    = o >> 11;
        int k    = s * 32 + (lane >> 4) * 8 + j;
        int col  = (lane & 15) + cb * 16;
        float v  = (k < 256) ? wa[k * 64 + col] : wb[(k - 256) * 64 + col];
        wt[o] = (__bf16)v;
    }
}

template <bool DIRECT_W>
__global__ __launch_bounds__(512, 4)
void agg_gemm_kernel(const float* __restrict__ xa,
                     const float* __restrict__ xb,
                     const float* __restrict__ wa,
                     const float* __restrict__ wb,
                     const __bf16* __restrict__ wt,
                     float* __restrict__ out) {
    // wave-private x transpose buffers: 8 waves x 4KB (16 rows x 256B bf16)
    __shared__ __align__(16) __bf16 xlds[8 * 2048];

    const int t    = threadIdx.x;
    const int lane = t & 63;
    const int wave = t >> 6;
    char* xbuf = (char*)&xlds[wave * 2048];

    const int    gw  = blockIdx.x * 8 + wave;   // wave tile id 0..4095
    const size_t R   = (size_t)gw * 16;         // first output row
    const int    l5  = lane >> 5;               // load row parity
    const int    l31 = lane & 31;
    const int    col = lane & 15;               // frag row (A) / col (D)
    const int    kg  = lane >> 4;               // k-group 0..3

    // ---- phase p: 16 rows x 128 K-floats of (p<2 ? xa : xb), half p&1 ----
    // load: instr i covers rows 2i,2i+1 as two contiguous 512B segments.
    auto issue = [&](int p, f32x4 (&r)[8]) {
        const float* X    = (p < 2) ? xa : xb;
        const float* base = X + R * 256 + (p & 1) * 128 + l31 * 4;
        #pragma unroll
        for (int i = 0; i < 8; ++i)
            r[i] = *(const f32x4*)(base + (size_t)(2 * i + l5) * 256);
    };

    // convert + swizzled LDS write (row-XOR, 16B granule; R4-verified 0-conflict)
    auto cvt_write = [&](const f32x4 (&r)[8]) {
        #pragma unroll
        for (int i = 0; i < 8; ++i) {
            const int rl = 2 * i + l5;
            bf16x4 v;
            v[0] = (__bf16)r[i][0]; v[1] = (__bf16)r[i][1];
            v[2] = (__bf16)r[i][2]; v[3] = (__bf16)r[i][3];
            *(bf16x4*)(xbuf + rl * 256 + ((l31 * 8) ^ ((rl & 7) << 4))) = v;
        }
    };

    f32x4 acc[4];
    #pragma unroll
    for (int cb = 0; cb < 4; ++cb) acc[cb] = (f32x4){0.f, 0.f, 0.f, 0.f};

    const int xsw = (col & 7) << 4;

    auto compute = [&](int p) {
        #pragma unroll
        for (int s = 0; s < 4; ++s) {
            bf16x8 af = *(const bf16x8*)(xbuf + col * 256 +
                                         ((s * 64 + kg * 16) ^ xsw));
            const int sg = p * 4 + s;            // global k-step 0..15
            bf16x8 wf[4];
            if constexpr (!DIRECT_W) {
                const __bf16* wp = wt + (size_t)(sg * 4) * 512 + lane * 8;
                wf[0] = *(const bf16x8*)(wp);
                wf[1] = *(const bf16x8*)(wp + 512);
                wf[2] = *(const bf16x8*)(wp + 1024);
                wf[3] = *(const bf16x8*)(wp + 1536);
            } else {
                const int k0 = sg * 32 + kg * 8;
                const float* src = (sg < 8) ? wa : wb;
                const int    kk  = (sg < 8) ? k0 : (k0 - 256);
                #pragma unroll
                for (int cb = 0; cb < 4; ++cb)
                    #pragma unroll
                    for (int j = 0; j < 8; ++j)
                        wf[cb][j] = (__bf16)src[(kk + j) * 64 + col + cb * 16];
            }
            acc[0] = __builtin_amdgcn_mfma_f32_16x16x32_bf16(af, wf[0], acc[0], 0, 0, 0);
            acc[1] = __builtin_amdgcn_mfma_f32_16x16x32_bf16(af, wf[1], acc[1], 0, 0, 0);
            acc[2] = __builtin_amdgcn_mfma_f32_16x16x32_bf16(af, wf[2], acc[2], 0, 0, 0);
            acc[3] = __builtin_amdgcn_mfma_f32_16x16x32_bf16(af, wf[3], acc[3], 0, 0, 0);
        }
    };

    // ---- zero-barrier per-wave pipeline ----
    f32x4 rA[8], rB[8];
    issue(0, rA);
    issue(1, rB);
    cvt_write(rA);                          // waits only rA (counted vmcnt)
    compute(0);

    issue(2, rA);
    __builtin_amdgcn_sched_barrier(0);      // keep loads issued early
    cvt_write(rB);                          // in-order DS: after compute(0) reads
    compute(1);

    issue(3, rB);
    __builtin_amdgcn_sched_barrier(0);
    cvt_write(rA);
    compute(2);

    cvt_write(rB);
    compute(3);

    // ---- epilogue: D row = kg*4 + rr, D col = col + cb*16 ----
    float* po = out + (R + kg * 4) * 64 + col;
    #pragma unroll
    for (int rr = 0; rr < 4; ++rr) {
        po[rr * 64 +  0] = acc[0][rr];
        po[rr * 64 + 16] = acc[1][rr];
        po[rr * 64 + 32] = acc[2][rr];
        po[rr * 64 + 48] = acc[3][rr];
    }
}

extern "C" void kernel_launch(void* const* d_in, const int* in_sizes, int n_in,
                              void* d_out, int out_size, void* d_ws, size_t ws_size,
                              hipStream_t stream) {
    const float* xa = (const float*)d_in[0];
    const float* xb = (const float*)d_in[1];
    const float* wa = (const float*)d_in[2];
    const float* wb = (const float*)d_in[3];
    float* out = (float*)d_out;

    if (ws_size >= (size_t)WT_BYTES) {
        __bf16* wt = (__bf16*)d_ws;
        prep_wt_kernel<<<64, 256, 0, stream>>>(wa, wb, wt);
        agg_gemm_kernel<false><<<512, 512, 0, stream>>>(xa, xb, wa, wb, wt, out);
    } else {
        agg_gemm_kernel<true><<<512, 512, 0, stream>>>(xa, xb, wa, wb, nullptr, out);
    }
}